// Round 3
// baseline (621.368 us; speedup 1.0000x reference)
//
#include <hip/hip_runtime.h>
#include <cmath>

#define HW 307200        // 480*640
#define NB 8             // batches
#define NBASE 63         // input basis channels (ones channel prepended -> 64)
#define NCHUNK (HW/256)  // 1200 pixel chunks of 256
#define GRAM_BLKS 128    // gram blocks per batch
#define GQCAP 24         // line-group queue cap (16/chunk + 3 leftover)

// ---- workspace layout (floats) ----
#define XTY_OFF 0                        // 8 * 64
#define YTY_OFF (NB*64)                  // 8
#define NC_OFF  (YTY_OFF + NB)           // 8
#define ZERO_FLOATS (NC_OFF + NB)        // atomic-accumulated region ends here (528)
#define XTX_OFF ZERO_FLOATS              // 8 * 64*64 (written whole by reduce_kernel)
#define MP_OFF  (XTX_OFF + NB*64*64)     // 8 * 64*64 (upper-tri M, diag halved, /beta)
#define WV_OFF  (MP_OFF + NB*64*64)      // 8 * 64

// ---- output layout (floats) ----
#define OUT_W   (NB*HW)                  // weights after logits
#define OUT_VAR (OUT_W + NB*64)          // var after weights
// NOTE: gram partials (8*128*4096 = 16.8MB) are staged in out[], consumed by
// reduce_kernel BEFORE solve/predvar overwrite out. Stream-ordered.

__device__ __forceinline__ bool finitef(float x) {
    // fast-math-proof isfinite: exponent bits not all ones
    return (__float_as_uint(x) & 0x7f800000u) != 0x7f800000u;
}

// ============================================================
// Kernel 1: sparse masked Gram at LINE-GROUP granularity.
// ~5% valid pixels => 56% of 16-px lines contain >=1 valid px.
// Queue 16-px groups (any-valid); gather each group's 64 channels
// as 16-lane-contiguous 64B bursts (4 cache lines per instruction
// instead of 64 divergent 4B requests), zero-mask invalid pixels,
// and run the dense 64x64 register-tile outer product per 4 groups.
// Per-wave accs LDS-reduced; one coalesced 16KB partial per block.
// ============================================================
__global__ __launch_bounds__(256) void gram_kernel(
    const float* __restrict__ bases, const float* __restrict__ targets,
    float* __restrict__ ws, float* __restrict__ part)
{
    __shared__ float tile[64*68];   // [pixel][channel], stride 68; tail reused for Xty reduce
    __shared__ float sy[64];
    __shared__ float sm[64];
    __shared__ int   qg[GQCAP];     // group base index (pixel>>4)
    __shared__ int   qmsk[GQCAP];   // 16-bit valid mask
    __shared__ int   qn;

    const int t  = threadIdx.x;
    const int b  = blockIdx.y;
    const int wv = t >> 6;          // wave id 0..3
    const int l  = t & 63;          // lane
    const int ti = l >> 3, tj = l & 7;

    float acc[8][8];
#pragma unroll
    for (int i = 0; i < 8; i++)
#pragma unroll
        for (int j = 0; j < 8; j++) acc[i][j] = 0.f;
    float acc_xty = 0.f, acc_yty = 0.f, acc_n = 0.f;

    const float* __restrict__ basesb = bases + (long)b * NBASE * HW;
    const float* __restrict__ targb  = targets + (long)b * HW;

    if (t == 0) qn = 0;
    __syncthreads();

    auto compute_tile = [&]() {
#pragma unroll 2
        for (int pp = 0; pp < 16; ++pp) {
            const int p2 = wv * 16 + pp;
            const float4 r0 = *(const float4*)&tile[p2*68 + 8*ti];
            const float4 r1 = *(const float4*)&tile[p2*68 + 8*ti + 4];
            const float4 c0 = *(const float4*)&tile[p2*68 + 8*tj];
            const float4 c1 = *(const float4*)&tile[p2*68 + 8*tj + 4];
            const float rr[8] = {r0.x,r0.y,r0.z,r0.w,r1.x,r1.y,r1.z,r1.w};
            const float cc[8] = {c0.x,c0.y,c0.z,c0.w,c1.x,c1.y,c1.z,c1.w};
#pragma unroll
            for (int i = 0; i < 8; i++)
#pragma unroll
                for (int j = 0; j < 8; j++)
                    acc[i][j] = fmaf(rr[i], cc[j], acc[i][j]);
            // Xty: lane l owns channel l
            acc_xty = fmaf(sy[p2], tile[p2*68 + l], acc_xty);
        }
    };

    // gather one group into this wave's 16 tile rows (gi = group index)
    auto gather_group = [&](int gi) {
        const int pl  = l & 15;         // pixel within group
        const int ch4 = l >> 4;         // channel sub-slot 0..3
        const float mf = sm[wv*16 + pl];
        const float* __restrict__ gp = basesb + (long)gi * 16 + pl;
#pragma unroll
        for (int q = 0; q < 16; q++) {
            const int c = q*4 + ch4;
            float v;
            if (c == 0) v = mf;         // ones channel = mask (q==0, ch4==0 lanes)
            else        v = gp[(long)(c - 1) * HW] * mf;
            tile[(wv*16 + pl)*68 + c] = v;
        }
    };
    auto zero_group_rows = [&]() {
        const int pl  = l & 15;
        const int ch4 = l >> 4;
#pragma unroll
        for (int q = 0; q < 16; q++)
            tile[(wv*16 + pl)*68 + q*4 + ch4] = 0.f;
    };

    for (int j = blockIdx.x; j < NCHUNK; j += GRAM_BLKS) {
        // ---- append: coalesced target read, per-16px-group enqueue ----
        const int p = j * 256 + t;
        const float y = targb[p];
        const bool fin = finitef(y);
        if (fin) { acc_yty = fmaf(y, y, acc_yty); acc_n += 1.f; }
        const unsigned long long m = __ballot(fin);
        if ((l & 15) == 0) {            // lanes 0,16,32,48: one per group
            const unsigned gm = (unsigned)((m >> l) & 0xFFFFull);
            if (gm) {
                const int pos = atomicAdd(&qn, 1);
                qg[pos]   = p >> 4;
                qmsk[pos] = (int)gm;
            }
        }
        __syncthreads();
        int nq = qn;
        // ---- drain: 4 groups -> one dense masked 64-px tile ----
        while (nq >= 4) {
            const int base = nq - 4;
            if (t < 64) {
                const int gsel = t >> 4;
                const int gi   = qg[base + gsel];
                const int msk  = qmsk[base + gsel];
                const int pix  = gi*16 + (t & 15);
                const float yv = targb[pix];            // L1/L2-hot re-read
                const bool v   = (msk >> (t & 15)) & 1;
                sm[t] = v ? 1.f : 0.f;
                sy[t] = v ? yv : 0.f;
            }
            __syncthreads();
            gather_group(qg[base + wv]);
            __syncthreads();
            compute_tile();
            nq = base;
            __syncthreads();
        }
        if (t == 0) qn = nq;
        __syncthreads();
    }

    // ---- flush remainder (<4 groups) with zero padding ----
    {
        const int nq = qn;
        if (nq > 0) {
            if (t < 64) {
                const int gsel = t >> 4;
                if (gsel < nq) {
                    const int gi  = qg[gsel];
                    const int msk = qmsk[gsel];
                    const int pix = gi*16 + (t & 15);
                    const float yv = targb[pix];
                    const bool v   = (msk >> (t & 15)) & 1;
                    sm[t] = v ? 1.f : 0.f;
                    sy[t] = v ? yv : 0.f;
                } else { sm[t] = 0.f; sy[t] = 0.f; }
            }
            __syncthreads();
            if (wv < nq) gather_group(qg[wv]);
            else         zero_group_rows();
            __syncthreads();
            compute_tile();
        }
    }
    __syncthreads();

    // ---- cross-wave reduce of acc tiles into tile[0..4096) ----
    for (int w = 0; w < 4; ++w) {
        if (wv == w) {
#pragma unroll
            for (int i = 0; i < 8; i++)
#pragma unroll
                for (int j2 = 0; j2 < 8; j2++) {
                    const int e = (8*ti + i) * 64 + 8*tj + j2;
                    tile[e] = (w == 0) ? acc[i][j2] : tile[e] + acc[i][j2];
                }
        }
        __syncthreads();
    }
    // one coalesced 16KB partial per block, no atomics
    float* __restrict__ pb = part + (long)(b * GRAM_BLKS + blockIdx.x) * 4096;
#pragma unroll
    for (int k = 0; k < 4; ++k)
        *(float4*)&pb[t*16 + 4*k] = *(const float4*)&tile[t*16 + 4*k];

    // Xty: cross-wave reduce into tile[4096..4160), then 64 atomics/block
    for (int w = 0; w < 4; ++w) {
        if (wv == w) tile[4096 + l] = (w == 0) ? acc_xty : tile[4096 + l] + acc_xty;
        __syncthreads();
    }
    if (t < 64) atomicAdd(&ws[XTY_OFF + b*64 + t], tile[4096 + t]);

    // yty, N: wave shuffle reduce + one atomic per wave
#pragma unroll
    for (int off = 32; off; off >>= 1) {
        acc_yty += __shfl_down(acc_yty, off, 64);
        acc_n   += __shfl_down(acc_n,   off, 64);
    }
    if (l == 0) {
        atomicAdd(&ws[YTY_OFF + b], acc_yty);
        atomicAdd(&ws[NC_OFF  + b], acc_n);
    }
}

// ============================================================
// Kernel 1b: sum the 128 per-block XtX partials -> ws (coalesced)
// ============================================================
__global__ __launch_bounds__(256) void reduce_kernel(
    const float* __restrict__ part, float* __restrict__ ws)
{
    const int b = blockIdx.y;
    const int e = blockIdx.x * 256 + threadIdx.x;   // grid.x = 16 -> e in [0,4096)
    const float* __restrict__ pb = part + (long)b * GRAM_BLKS * 4096 + e;
    float s = 0.f;
#pragma unroll 8
    for (int k = 0; k < GRAM_BLKS; ++k)
        s += pb[(long)k * 4096];
    ws[XTX_OFF + b*4096 + e] = s;
}

// ============================================================
// Kernel 2: per batch, 64 threads = 1 wave (barriers ~free).
// Cholesky in LDS; explicit inverse with the W-column held in 64
// REGISTERS (fully unrolled, static indices) and L rows read as
// wave-uniform LDS broadcasts; one reciprocal per row instead of
// per-element divides. Mp emitted by COLUMN (thread t = column t,
// coalesced; W[j][t] = Wc[j], no symmetry assumption).
// ============================================================
__global__ __launch_bounds__(64) void solve_kernel(
    float* __restrict__ ws, float* __restrict__ out)
{
    __shared__ float A[64*65];
    __shared__ float d0[64], dinv_s[64], xty_s[64], wv_s[64];

    const int b = blockIdx.x;
    const int t = threadIdx.x;
    const float* XtX = ws + XTX_OFF + b * 4096;

    for (int e = t; e < 4096; e += 64)
        A[(e >> 6) * 65 + (e & 63)] = XtX[e];
    xty_s[t] = ws[XTY_OFF + b*64 + t];
    const float yty = ws[YTY_OFF + b];
    const float Nc  = ws[NC_OFF  + b];
    __syncthreads();
    d0[t] = A[t*65 + t];
    __syncthreads();

    // Cholesky (lower), upper triangle keeps original XtX
    for (int k = 0; k < 64; k++) {
        const float akk = A[k*65 + k];
        __syncthreads();
        const float dk = sqrtf(akk);
        if (t == k)      A[k*65 + k] = dk;
        else if (t > k)  A[t*65 + k] /= dk;
        __syncthreads();
        if (t > k) {
            const float ltk = A[t*65 + k];
            for (int j = k + 1; j <= t; j++)
                A[t*65 + j] -= ltk * A[j*65 + k];
        }
        __syncthreads();
    }

    dinv_s[t] = 1.f / A[t*65 + t];
    __syncthreads();

    // W = (L L^T)^-1, column t in registers
    float Wc[64];
    // forward: L Y = e_t
#pragma unroll
    for (int i = 0; i < 64; i++) {
        float s0 = (i == t) ? 1.f : 0.f, s1 = 0.f, s2 = 0.f, s3 = 0.f;
        const int nfull = i >> 2;
#pragma unroll
        for (int qd = 0; qd < nfull; qd++) {
            const int j = qd * 4;
            s0 = fmaf(-A[i*65 + j    ], Wc[j    ], s0);
            s1 = fmaf(-A[i*65 + j + 1], Wc[j + 1], s1);
            s2 = fmaf(-A[i*65 + j + 2], Wc[j + 2], s2);
            s3 = fmaf(-A[i*65 + j + 3], Wc[j + 3], s3);
        }
#pragma unroll
        for (int j = nfull * 4; j < i; j++)
            s0 = fmaf(-A[i*65 + j], Wc[j], s0);
        Wc[i] = ((s0 + s1) + (s2 + s3)) * dinv_s[i];
    }
    // backward: L^T W = Y
#pragma unroll
    for (int i = 63; i >= 0; i--) {
        float s0 = Wc[i], s1 = 0.f, s2 = 0.f, s3 = 0.f;
        const int j0 = i + 1;
        const int nfull = (64 - j0) >> 2;
#pragma unroll
        for (int qd = 0; qd < nfull; qd++) {
            const int j = j0 + qd * 4;
            s0 = fmaf(-A[(j    )*65 + i], Wc[j    ], s0);
            s1 = fmaf(-A[(j + 1)*65 + i], Wc[j + 1], s1);
            s2 = fmaf(-A[(j + 2)*65 + i], Wc[j + 2], s2);
            s3 = fmaf(-A[(j + 3)*65 + i], Wc[j + 3], s3);
        }
#pragma unroll
        for (int j = j0 + nfull * 4; j < 64; j++)
            s0 = fmaf(-A[j*65 + i], Wc[j], s0);
        Wc[i] = ((s0 + s1) + (s2 + s3)) * dinv_s[i];
    }

    // w_t = sum_j W[j][t] * xty[j]  (= (W xty)_t, W symmetric)
    float w0 = 0.f, w1 = 0.f, w2 = 0.f, w3 = 0.f;
#pragma unroll
    for (int j = 0; j < 64; j += 4) {
        w0 = fmaf(Wc[j    ], xty_s[j    ], w0);
        w1 = fmaf(Wc[j + 1], xty_s[j + 1], w1);
        w2 = fmaf(Wc[j + 2], xty_s[j + 2], w2);
        w3 = fmaf(Wc[j + 3], xty_s[j + 3], w3);
    }
    const float wt = (w0 + w1) + (w2 + w3);
    wv_s[t] = wt;
    __syncthreads();

    // E_d = yty - 2 w.Xty + w.(XtX w)  (XtX from upper triangle + saved diag)
    float qt = 0.f;
#pragma unroll
    for (int j = 0; j < 64; j++) {
        const float x = (j > t) ? A[t*65 + j] : ((j == t) ? d0[t] : A[j*65 + t]);
        qt = fmaf(x, wv_s[j], qt);
    }
    float r1 = wt * xty_s[t];
    float r2 = wt * qt;
#pragma unroll
    for (int off = 32; off; off >>= 1) {
        r1 += __shfl_down(r1, off, 64);
        r2 += __shfl_down(r2, off, 64);
    }
    r1 = __shfl(r1, 0, 64);
    r2 = __shfl(r2, 0, 64);
    const float E_d = yty - 2.f * r1 + r2;

    // EM beta loop (uniform on all lanes), faithful to reference latch order
    float beta0 = sqrtf(Nc);
    float beta  = beta0;
    bool  done  = false;
#pragma unroll
    for (int it = 0; it < 5; ++it) {
        const float Tr_d = 64.f / beta;
        const float beta_new = Nc / (E_d + Tr_d);
        const bool conv = fabsf(beta_new / beta0 - 1.f) < 0.02f;
        if (!done) { beta = beta_new; beta0 = beta_new; }
        done = done || conv;
    }
    const float ib = 1.f / beta;

    out[OUT_W + b*64 + t] = wt;
    ws[WV_OFF + b*64 + t] = wt;
    // Mp[row j][col t]: zero below diag, 0.5x diag, * 1/beta. Coalesced column write.
    float* __restrict__ Mp = ws + MP_OFF + b * 4096;
#pragma unroll
    for (int j = 0; j < 64; j++) {
        const float v = (j > t) ? 0.f : ((j == t) ? 0.5f : 1.f) * Wc[j] * ib;
        Mp[j*64 + t] = v;
    }
}

// ============================================================
// Kernel 3: 2 pixels/thread: pred = w.b, var = 2*sum_i b_i*sum_{j>=i} Mp[i][j] b_j
// Mp staged in LDS (16KB), wave-uniform ds_read_b128 broadcasts.
// ============================================================
__global__ __launch_bounds__(256, 2) void predvar_kernel(
    const float* __restrict__ bases, const float* __restrict__ ws,
    float* __restrict__ out)
{
    __shared__ float Mp_s[4096];
    __shared__ float w_s[64];

    const int b = blockIdx.y;
    const int t = threadIdx.x;
    {
        const float4* __restrict__ src = (const float4*)(ws + MP_OFF + b * 4096);
        float4* dst = (float4*)Mp_s;
        for (int e = t; e < 1024; e += 256) dst[e] = src[e];
        if (t < 64) w_s[t] = ws[WV_OFF + b*64 + t];
    }
    __syncthreads();

    const int pix = (blockIdx.x * 256 + t) * 2;
    const float* basesb = bases + (long)b * NBASE * HW + pix;

    float2 bv[64];
    bv[0] = make_float2(1.f, 1.f);
#pragma unroll
    for (int c = 1; c < 64; c++)
        bv[c] = *(const float2*)&basesb[(long)(c - 1) * HW];

    float px = w_s[0], py = w_s[0];
#pragma unroll
    for (int c = 1; c < 64; c++) {
        px = fmaf(w_s[c], bv[c].x, px);
        py = fmaf(w_s[c], bv[c].y, py);
    }

    float vx = 0.f, vy = 0.f;
#pragma unroll
    for (int i = 0; i < 64; i++) {
        float sx = 0.f, sy2 = 0.f;
#pragma unroll
        for (int qd = i >> 2; qd < 16; qd++) {
            const float4 m = *(const float4*)&Mp_s[i*64 + 4*qd];
            sx  = fmaf(m.x, bv[4*qd+0].x, sx);
            sy2 = fmaf(m.x, bv[4*qd+0].y, sy2);
            sx  = fmaf(m.y, bv[4*qd+1].x, sx);
            sy2 = fmaf(m.y, bv[4*qd+1].y, sy2);
            sx  = fmaf(m.z, bv[4*qd+2].x, sx);
            sy2 = fmaf(m.z, bv[4*qd+2].y, sy2);
            sx  = fmaf(m.w, bv[4*qd+3].x, sx);
            sy2 = fmaf(m.w, bv[4*qd+3].y, sy2);
        }
        vx = fmaf(sx,  bv[i].x, vx);
        vy = fmaf(sy2, bv[i].y, vy);
    }

    *(float2*)&out[(long)b * HW + pix] = make_float2(px, py);
    *(float2*)&out[OUT_VAR + (long)b * HW + pix] = make_float2(2.f * vx, 2.f * vy);
}

extern "C" void kernel_launch(void* const* d_in, const int* in_sizes, int n_in,
                              void* d_out, int out_size, void* d_ws, size_t ws_size,
                              hipStream_t stream)
{
    const float* bases   = (const float*)d_in[0];
    const float* targets = (const float*)d_in[1];
    float* out = (float*)d_out;
    float* ws  = (float*)d_ws;

    // zero only the atomic-accumulated region (Xty/yty/N); XtX is written whole
    hipMemsetAsync(d_ws, 0, ZERO_FLOATS * sizeof(float), stream);

    // XtX partials staged in out[] (dead until reduce consumes them)
    gram_kernel<<<dim3(GRAM_BLKS, NB), 256, 0, stream>>>(bases, targets, ws, out);
    reduce_kernel<<<dim3(16, NB), 256, 0, stream>>>(out, ws);
    solve_kernel<<<NB, 64, 0, stream>>>(ws, out);
    predvar_kernel<<<dim3(HW / 512, NB), 256, 0, stream>>>(bases, ws, out);
}